// Round 9
// baseline (459.913 us; speedup 1.0000x reference)
//
#include <hip/hip_runtime.h>
#include <hip/hip_bf16.h>
#include <hip/hip_fp16.h>

#define NNODES 100000
#define NEDGES 1600000
#define ETOT   (NEDGES + NNODES)
#define SCANB  1024
#define NSCAN  ((NNODES + SCANB - 1) / SCANB)  // 98
#define NB     782                              // buckets of 128 nodes (dst>>7)
#define NBINBLK 256                             // blocks for privatized binning

typedef _Float16 half8 __attribute__((ext_vector_type(8)));
typedef float f32x4 __attribute__((ext_vector_type(4)));

struct WSrc { const void* p[12]; };

__device__ __forceinline__ float ld_f(const void* p, long i, int f32) {
  if (f32) return ((const float*)p)[i];
  return __bfloat162float(((const __hip_bfloat16*)p)[i]);
}

__device__ __forceinline__ unsigned short f2bf_bits(float v) {
  __hip_bfloat16 b = __float2bfloat16(v);
  return __builtin_bit_cast(unsigned short, b);
}

// ---------------- dtype detection ----------------
// flags[0]: 1 => edge_index is int64, else int32
// flags[1]: 1 => float buffers are fp32, else bf16
__global__ void detect_kernel(const void* xraw, const void* eraw, int* flags) {
  __shared__ int cnt0, cnt1;
  if (threadIdx.x == 0) { cnt0 = 0; cnt1 = 0; }
  __syncthreads();
  const int* e32 = (const int*)eraw;
  int nz = 0;
  for (int i = threadIdx.x; i < 2048; i += blockDim.x) nz += (e32[2 * i + 1] != 0);
  const unsigned short* xs = (const unsigned short*)xraw;
  int weird = 0;
  for (int i = threadIdx.x; i < 4096; i += blockDim.x) {
    unsigned short u = xs[2 * i];
    int ex = (u >> 7) & 0xFF;
    weird += (ex > 168 || (ex < 88 && ex != 0)) ? 1 : 0;
  }
  atomicAdd(&cnt0, nz);
  atomicAdd(&cnt1, weird);
  __syncthreads();
  if (threadIdx.x == 0) {
    flags[0] = (cnt0 < 1024) ? 1 : 0;
    flags[1] = (cnt1 > 512) ? 1 : 0;
  }
}

// ---------------- weights to fp32 (+ fused fp16 W^T production) ----------------
__global__ void conv_wts_kernel(WSrc wsrc, float* dst, __half* Wt, const int* flags) {
  const int start[13] = {0, 16384, 16512, 16640, 16768, 33152, 33280, 33408,
                         33536, 49920, 50048, 50176, 50304};
  int f32 = flags[1];
  int stride = gridDim.x * blockDim.x;
  for (int i = blockIdx.x * blockDim.x + threadIdx.x; i < 50304; i += stride) {
    int s = 0;
    while (start[s + 1] <= i) s++;
    float v = ld_f(wsrc.p[s], i - start[s], f32);
    dst[i] = v;
    if (s == 0 || s == 4 || s == 8) {  // W regions -> transposed fp16 Wt[layer][col][k]
      int layer = s >> 2;
      int rem = i - start[s];
      int k = rem >> 7, c = rem & 127;
      Wt[layer * 16384 + c * 128 + k] = __float2half(v);
    }
  }
}

// ---------------- bucketed CSR build (block-privatized) ----------------
__device__ __forceinline__ void load_edge(const void* raw, int i64, long e, int& s, int& d) {
  if (i64) {
    const long long* r = (const long long*)raw;
    s = (int)r[e];
    d = (int)r[NEDGES + e];
  } else {
    const int* r = (const int*)raw;
    s = r[e];
    d = r[NEDGES + e];
  }
}

__device__ __forceinline__ int load_dst(const void* raw, int i64, long e) {
  if (i64) return (int)((const long long*)raw)[NEDGES + e];
  return ((const int*)raw)[NEDGES + e];
}

// privatized bucket histogram: LDS counts, one global add per (block,bucket)
__global__ __launch_bounds__(256) void binhist(const void* raw, const int* flags, int* bcnt) {
  __shared__ int h[NB];
  for (int t = threadIdx.x; t < NB; t += 256) h[t] = 0;
  __syncthreads();
  int i64 = flags[0];
  long per = (NEDGES + NBINBLK - 1) / NBINBLK;
  long lo = (long)blockIdx.x * per;
  long hi = lo + per; if (hi > NEDGES) hi = NEDGES;
  for (long e = lo + threadIdx.x; e < hi; e += 256)
    atomicAdd(&h[load_dst(raw, i64, e) >> 7], 1);
  __syncthreads();
  for (int t = threadIdx.x; t < NB; t += 256) {
    int c = h[t];
    if (c) atomicAdd(&bcnt[t], c);
  }
}

__global__ __launch_bounds__(1024) void binscan(const int* bcnt, int* boff, int* bcur) {
  __shared__ int lds[1024];
  int t = threadIdx.x;
  int x = (t < NB) ? bcnt[t] : 0;
  lds[t] = x;
  __syncthreads();
  for (int off = 1; off < 1024; off <<= 1) {
    int v = (t >= off) ? lds[t - off] : 0;
    __syncthreads();
    lds[t] += v;
    __syncthreads();
  }
  int excl = lds[t] - x;
  if (t < NB) { boff[t] = excl; bcur[t] = excl; }
  if (t == 0) boff[NB] = NEDGES;
}

// privatized placement. ebuf entry packed: src (17 bits) | (dst&127) << 17
__global__ __launch_bounds__(256) void binplace(const void* raw, const int* flags, int* bcur,
                                                int* ebuf) {
  __shared__ int hist[NB];
  __shared__ int base[NB];
  int i64 = flags[0];
  long per = (NEDGES + NBINBLK - 1) / NBINBLK;
  long lo = (long)blockIdx.x * per;
  long hi = lo + per; if (hi > NEDGES) hi = NEDGES;
  for (int t = threadIdx.x; t < NB; t += 256) hist[t] = 0;
  __syncthreads();
  for (long e = lo + threadIdx.x; e < hi; e += 256)
    atomicAdd(&hist[load_dst(raw, i64, e) >> 7], 1);
  __syncthreads();
  for (int t = threadIdx.x; t < NB; t += 256) {
    int c = hist[t];
    base[t] = c ? atomicAdd(&bcur[t], c) : 0;
    hist[t] = 0;
  }
  __syncthreads();
  for (long e = lo + threadIdx.x; e < hi; e += 256) {
    int s, d;
    load_edge(raw, i64, e, s, d);
    int b = d >> 7;
    int pos = base[b] + atomicAdd(&hist[b], 1);
    ebuf[pos] = s | ((d & 127) << 17);
  }
}

// per-bucket degree histogram (LDS), real edges only
__global__ __launch_bounds__(256) void deghist(const int* ebuf, const int* boff, int* deg) {
  __shared__ int h[128];
  int b = blockIdx.x, t = threadIdx.x;
  if (t < 128) h[t] = 0;
  __syncthreads();
  int beg = boff[b], end = boff[b + 1];
  for (int i = beg + t; i < end; i += 256) atomicAdd(&h[ebuf[i] >> 17], 1);
  __syncthreads();
  int node = b * 128 + t;
  if (t < 128 && node < NNODES) deg[node] = h[t];
}

// ---------------- multi-block exclusive scan of (deg[i]+1) ----------------
__global__ __launch_bounds__(1024) void scan_part(const int* deg, int* part) {
  __shared__ int lds[SCANB];
  int b = blockIdx.x, t = threadIdx.x;
  int idx = b * SCANB + t;
  lds[t] = (idx < NNODES) ? deg[idx] + 1 : 0;
  __syncthreads();
  for (int off = 512; off > 0; off >>= 1) {
    if (t < off) lds[t] += lds[t + off];
    __syncthreads();
  }
  if (t == 0) part[b] = lds[0];
}

__global__ __launch_bounds__(128) void scan_tops(int* part) {
  __shared__ int lds[128];
  int t = threadIdx.x;
  lds[t] = (t < NSCAN) ? part[t] : 0;
  __syncthreads();
  for (int off = 1; off < 128; off <<= 1) {
    int v = (t >= off) ? lds[t - off] : 0;
    __syncthreads();
    lds[t] += v;
    __syncthreads();
  }
  if (t < NSCAN) part[t] = (t == 0) ? 0 : lds[t - 1];
}

__global__ __launch_bounds__(1024) void scan_write(const int* deg, const int* part, int* rs) {
  __shared__ int lds[SCANB];
  int b = blockIdx.x, t = threadIdx.x;
  int idx = b * SCANB + t;
  int x = (idx < NNODES) ? deg[idx] + 1 : 0;
  lds[t] = x;
  __syncthreads();
  for (int off = 1; off < SCANB; off <<= 1) {
    int v = (t >= off) ? lds[t - off] : 0;
    __syncthreads();
    lds[t] += v;
    __syncthreads();
  }
  int incl = part[b] + lds[t];
  int excl = incl - x;
  if (idx < NNODES) rs[idx] = excl;
  if (idx == NNODES - 1) rs[NNODES] = incl;
}

// per-bucket scatter with LDS cursors; adj writes land in a contiguous window
__global__ __launch_bounds__(256) void bucket_scatter(const int* ebuf, const int* boff,
                                                      const int* rs, int* adj) {
  __shared__ int cur[128];
  int b = blockIdx.x, t = threadIdx.x;
  int node = b * 128 + t;
  if (t < 128) cur[t] = (node < NNODES) ? rs[node] : 0;
  __syncthreads();
  int beg = boff[b], end = boff[b + 1];
  for (int i = beg + t; i < end; i += 256) {
    int v = ebuf[i];
    int pos = atomicAdd(&cur[v >> 17], 1);
    adj[pos] = v & 0x1FFFF;
  }
  __syncthreads();
  if (t < 128 && node < NNODES) adj[cur[t]] = node;  // self-loop appended last
}

// ---------------- MFMA GEMM + fused attention terms ----------------
template <int H, int SRC>  // SRC: 1 = raw x (bf16/fp32 by flag), 0 = fp16
__global__ __launch_bounds__(256) void gemm_mfma(const void* Araw, const float* wts,
                                                 const __half* Wt, int as_off, int ad_off,
                                                 __half* G, float* al, float* ar,
                                                 const int* flags) {
  __shared__ unsigned short Wl[128 * 128];
  __shared__ unsigned short Al[64 * 128];
  const int tid = threadIdx.x;
  const int rowbase = blockIdx.x * 64;
  for (int i = tid; i < 2048; i += 256) {
    int col = i >> 4, kc = i & 15;
    ((uint4*)Wl)[col * 16 + (kc ^ (col & 7))] = ((const uint4*)Wt)[i];
  }
  if (SRC == 0) {
    const __half* A = (const __half*)Araw;
    for (int i = tid; i < 1024; i += 256) {
      int row = i >> 4, kc = i & 15;
      int grow = rowbase + row;
      uint4 v = {0, 0, 0, 0};
      if (grow < NNODES) v = *(const uint4*)&A[(size_t)grow * 128 + kc * 8];
      ((uint4*)Al)[row * 16 + (kc ^ (row & 7))] = v;
    }
  } else {
    int f32 = flags[1];
    for (int i = tid; i < 1024; i += 256) {
      int row = i >> 4, kc = i & 15;
      int grow = rowbase + row;
      _Float16 tmp[8];
#pragma unroll
      for (int j = 0; j < 8; j++) tmp[j] = (_Float16)0.f;
      if (grow < NNODES) {
        if (f32) {
          const float* A = (const float*)Araw;
#pragma unroll
          for (int j = 0; j < 8; j++) tmp[j] = (_Float16)A[(size_t)grow * 128 + kc * 8 + j];
        } else {
          const __hip_bfloat16* A = (const __hip_bfloat16*)Araw;
#pragma unroll
          for (int j = 0; j < 8; j++)
            tmp[j] = (_Float16)__bfloat162float(A[(size_t)grow * 128 + kc * 8 + j]);
        }
      }
      ((uint4*)Al)[row * 16 + (kc ^ (row & 7))] = *(const uint4*)tmp;
    }
  }
  __syncthreads();
  int wv = tid >> 6, l = tid & 63;
  int lr = l & 15, lg = l >> 4;
  f32x4 acc[8];
#pragma unroll
  for (int n = 0; n < 8; n++) acc[n] = (f32x4){0.f, 0.f, 0.f, 0.f};
  int arow = wv * 16 + lr;
#pragma unroll
  for (int ks = 0; ks < 4; ks++) {
    half8 a = *(const half8*)&Al[(arow * 16 + ((ks * 4 + lg) ^ (arow & 7))) * 8];
#pragma unroll
    for (int n = 0; n < 8; n++) {
      int wrow = n * 16 + lr;
      half8 bf = *(const half8*)&Wl[(wrow * 16 + ((ks * 4 + lg) ^ (wrow & 7))) * 8];
      acc[n] = __builtin_amdgcn_mfma_f32_16x16x32_f16(a, bf, acc[n], 0, 0, 0);
    }
  }
  float as_row[8], ad_row[8];
#pragma unroll
  for (int n = 0; n < 8; n++) {
    as_row[n] = wts[as_off + n * 16 + lr];
    ad_row[n] = wts[ad_off + n * 16 + lr];
  }
  if (H == 4) {
    float pa[4][4], pb[4][4];
#pragma unroll
    for (int j = 0; j < 4; j++)
#pragma unroll
      for (int h = 0; h < 4; h++) {
        pa[j][h] = acc[2 * h][j] * as_row[2 * h] + acc[2 * h + 1][j] * as_row[2 * h + 1];
        pb[j][h] = acc[2 * h][j] * ad_row[2 * h] + acc[2 * h + 1][j] * ad_row[2 * h + 1];
      }
#pragma unroll
    for (int msk = 1; msk <= 8; msk <<= 1)
#pragma unroll
      for (int j = 0; j < 4; j++)
#pragma unroll
        for (int h = 0; h < 4; h++) {
          pa[j][h] += __shfl_xor(pa[j][h], msk, 64);
          pb[j][h] += __shfl_xor(pb[j][h], msk, 64);
        }
    if (lr == 0) {
#pragma unroll
      for (int j = 0; j < 4; j++) {
        int gr = rowbase + wv * 16 + lg * 4 + j;
        if (gr < NNODES) {
#pragma unroll
          for (int h = 0; h < 4; h++) {
            al[(size_t)gr * 4 + h] = pa[j][h];
            ar[(size_t)gr * 4 + h] = pb[j][h];
          }
        }
      }
    }
  } else {
    float pa[4], pb[4];
#pragma unroll
    for (int j = 0; j < 4; j++) {
      pa[j] = 0.f;
      pb[j] = 0.f;
#pragma unroll
      for (int n = 0; n < 8; n++) {
        pa[j] = fmaf(acc[n][j], as_row[n], pa[j]);
        pb[j] = fmaf(acc[n][j], ad_row[n], pb[j]);
      }
    }
#pragma unroll
    for (int msk = 1; msk <= 8; msk <<= 1)
#pragma unroll
      for (int j = 0; j < 4; j++) {
        pa[j] += __shfl_xor(pa[j], msk, 64);
        pb[j] += __shfl_xor(pb[j], msk, 64);
      }
    if (lr == 0) {
#pragma unroll
      for (int j = 0; j < 4; j++) {
        int gr = rowbase + wv * 16 + lg * 4 + j;
        if (gr < NNODES) { al[gr] = pa[j]; ar[gr] = pb[j]; }
      }
    }
  }
  __syncthreads();
#pragma unroll
  for (int n = 0; n < 8; n++)
#pragma unroll
    for (int j = 0; j < 4; j++) {
      int r = wv * 16 + lg * 4 + j;
      Al[r * 128 + n * 16 + lr] = __builtin_bit_cast(unsigned short, (_Float16)acc[n][j]);
    }
  __syncthreads();
  for (int i = tid; i < 1024; i += 256) {
    int row = i >> 4, kc = i & 15;
    int grow = rowbase + row;
    if (grow < NNODES) *(uint4*)&G[(size_t)grow * 128 + kc * 8] = ((const uint4*)Al)[i];
  }
}

// ---------------- flash aggregation: 32-edge chunks, 2 lanes/edge ----------------
// One wave per dst node. Edge j at lanes {2j, 2j+1}: even lane holds heads 0,1
// (p0,p1), odd lane heads 2,3 (H=4). Gather: lane owns channels (2l,2l+1),
// head hA = l>>4; alpha for head hA of edge j lives at lane 2j+(hA>>1), slot (hA&1).
// Reader-side selection: shuffle BOTH slots, pick by reader's sel.
template <int H, int RELU, int OUTCONV>
__global__ __launch_bounds__(256) void aggregate4(const __half* G, const float* al, const float* ar,
                                                  const float* wts, int b_off, const int* rs,
                                                  const int* adj, void* out, const int* flags) {
  int node = blockIdx.x * 4 + (threadIdx.x >> 6);
  if (node >= NNODES) return;
  int l = threadIdx.x & 63;
  int hA = l >> 4;
  int sel = (H == 4) ? (hA & 1) : 0;
  int srcoff = (H == 4) ? (hA >> 1) : 0;
  int hh0 = (H == 4) ? ((l & 1) * 2) : 0;
  float ar0, ar1;
  if (H == 4) {
    float2 a2 = *(const float2*)&ar[(size_t)node * 4 + hh0];
    ar0 = a2.x; ar1 = a2.y;
  } else {
    ar0 = ar[node]; ar1 = 0.f;
  }
  int beg = rs[node], end = rs[node + 1];
  float m0 = -1e30f, m1 = -1e30f, sum0 = 0.f, sum1 = 0.f;
  float accx = 0.f, accy = 0.f;
  for (int base = beg; base < end; base += 32) {
    int nj = end - base; if (nj > 32) nj = 32;  // wave-uniform
    int slot = base + (l >> 1);
    bool valid = slot < end;
    int s = valid ? adj[slot] : 0;
    // softmax inputs (one random 8B load per lane covers 2 heads)
    float av0, av1;
    if (H == 4) {
      float2 a2 = *(const float2*)&al[(size_t)s * 4 + hh0];
      av0 = a2.x; av1 = a2.y;
    } else { av0 = al[s]; av1 = 0.f; }
    // stage up to 32 G-row channel pairs; row index broadcast via readlane (scalar)
    __half2 g[32];
#pragma unroll
    for (int j = 0; j < 32; j++) {
      if (j < nj) {
        int sj = __builtin_amdgcn_readlane(s, 2 * j);
        g[j] = *(const __half2*)&G[(size_t)sj * 128 + 2 * l];
      }
    }
    // softmax (overlaps staged-load latency). xor masks skip bit0: reduction
    // stays within the parity class; each class contains all 32 edges.
    float v0 = av0 + ar0;
    float e0 = valid ? ((v0 > 0.f) ? v0 : 0.2f * v0) : -1e30f;
    float e1 = 0.f;
    if (H == 4) {
      float v1 = av1 + ar1;
      e1 = valid ? ((v1 > 0.f) ? v1 : 0.2f * v1) : -1e30f;
    }
    float c0 = e0, c1 = e1;
#pragma unroll
    for (int msk = 2; msk <= 32; msk <<= 1) {
      c0 = fmaxf(c0, __shfl_xor(c0, msk, 64));
      if (H == 4) c1 = fmaxf(c1, __shfl_xor(c1, msk, 64));
    }
    float mn0 = fmaxf(m0, c0);
    float sc0 = __expf(m0 - mn0);
    float p0 = __expf(e0 - mn0);
    float cs0 = p0;
    float mn1 = 0.f, sc1 = 0.f, p1 = 0.f, cs1 = 0.f;
    if (H == 4) {
      mn1 = fmaxf(m1, c1);
      sc1 = __expf(m1 - mn1);
      p1 = __expf(e1 - mn1);
      cs1 = p1;
    }
#pragma unroll
    for (int msk = 2; msk <= 32; msk <<= 1) {
      cs0 += __shfl_xor(cs0, msk, 64);
      if (H == 4) cs1 += __shfl_xor(cs1, msk, 64);
    }
    sum0 = sum0 * sc0 + cs0;
    m0 = mn0;
    if (H == 4) { sum1 = sum1 * sc1 + cs1; m1 = mn1; }
    // chunk rescale factor for this lane's head (reader-side select)
    float scA;
    if (H == 4) {
      float t0 = __shfl(sc0, srcoff, 64);
      float t1 = __shfl(sc1, srcoff, 64);
      scA = sel ? t1 : t0;
    } else {
      scA = __shfl(sc0, 0, 64);
    }
    accx *= scA;
    accy *= scA;
#pragma unroll
    for (int j = 0; j < 32; j++) {
      if (j < nj) {
        float aA;
        if (H == 4) {
          float t0 = __shfl(p0, 2 * j + srcoff, 64);
          float t1 = __shfl(p1, 2 * j + srcoff, 64);
          aA = sel ? t1 : t0;
        } else {
          aA = __shfl(p0, 2 * j, 64);
        }
        float2 g2 = __half22float2(g[j]);
        accx = fmaf(aA, g2.x, accx);
        accy = fmaf(aA, g2.y, accy);
      }
    }
  }
  float smA;
  if (H == 4) {
    float t0 = __shfl(sum0, srcoff, 64);
    float t1 = __shfl(sum1, srcoff, 64);
    smA = sel ? t1 : t0;
  } else {
    smA = __shfl(sum0, 0, 64);
  }
  float inv = 1.f / (smA + 1e-16f);
  float2 b2 = *(const float2*)&wts[b_off + 2 * l];
  float ox = accx * inv + b2.x;
  float oy = accy * inv + b2.y;
  if (RELU) {
    ox = fmaxf(ox, 0.f);
    oy = fmaxf(oy, 0.f);
  }
  size_t oi = (size_t)node * 128 + 2 * l;
  if (OUTCONV) {
    if (flags[1]) {
      *(float2*)&((float*)out)[oi] = make_float2(ox, oy);
    } else {
      *(ushort2*)&((unsigned short*)out)[oi] = make_ushort2(f2bf_bits(ox), f2bf_bits(oy));
    }
  } else {
    *(__half2*)&((__half*)out)[oi] = __floats2half2_rn(ox, oy);
  }
}

extern "C" void kernel_launch(void* const* d_in, const int* in_sizes, int n_in,
                              void* d_out, int out_size, void* d_ws, size_t ws_size,
                              hipStream_t stream) {
  char* ws = (char*)d_ws;
  size_t cur = 0;
  auto alloc = [&](size_t bytes) {
    size_t o = cur;
    cur += (bytes + 255) & ~(size_t)255;
    return o;
  };
  size_t off_flags = alloc(256);
  size_t off_wts = alloc(50304 * 4);
  size_t off_wt = alloc(3 * 16384 * 2);
  size_t off_ebuf = alloc((size_t)NEDGES * 4);
  size_t off_bcnt = alloc((size_t)NB * 4);
  size_t off_boff = alloc(((size_t)NB + 1) * 4);
  size_t off_bcur = alloc((size_t)NB * 4);
  size_t off_deg = alloc((size_t)NNODES * 4);
  size_t off_part = alloc((size_t)NSCAN * 4 + 256);
  size_t off_rs = alloc(((size_t)NNODES + 1) * 4);
  size_t off_adj = alloc((size_t)ETOT * 4);
  size_t off_al = alloc((size_t)NNODES * 4 * 4);
  size_t off_ar = alloc((size_t)NNODES * 4 * 4);
  size_t off_g = alloc((size_t)NNODES * 128 * 2);
  size_t off_ha = alloc((size_t)NNODES * 128 * 2);
  size_t off_hb = alloc((size_t)NNODES * 128 * 2);

  int* flags = (int*)(ws + off_flags);
  float* wts = (float*)(ws + off_wts);
  __half* Wt = (__half*)(ws + off_wt);
  int* ebuf = (int*)(ws + off_ebuf);
  int* bcnt = (int*)(ws + off_bcnt);
  int* boff = (int*)(ws + off_boff);
  int* bcur = (int*)(ws + off_bcur);
  int* deg = (int*)(ws + off_deg);
  int* part = (int*)(ws + off_part);
  int* rs = (int*)(ws + off_rs);
  int* adj = (int*)(ws + off_adj);
  float* al = (float*)(ws + off_al);
  float* ar = (float*)(ws + off_ar);
  __half* G = (__half*)(ws + off_g);
  __half* ha = (__half*)(ws + off_ha);
  __half* hb = (__half*)(ws + off_hb);

  detect_kernel<<<1, 256, 0, stream>>>(d_in[0], d_in[1], flags);

  WSrc wsrc;
  for (int i = 0; i < 12; i++) wsrc.p[i] = d_in[2 + i];
  conv_wts_kernel<<<64, 256, 0, stream>>>(wsrc, wts, Wt, flags);

  (void)hipMemsetAsync(bcnt, 0, (size_t)NB * 4, stream);
  binhist<<<NBINBLK, 256, 0, stream>>>(d_in[1], flags, bcnt);
  binscan<<<1, 1024, 0, stream>>>(bcnt, boff, bcur);
  binplace<<<NBINBLK, 256, 0, stream>>>(d_in[1], flags, bcur, ebuf);
  deghist<<<NB, 256, 0, stream>>>(ebuf, boff, deg);
  scan_part<<<NSCAN, 1024, 0, stream>>>(deg, part);
  scan_tops<<<1, 128, 0, stream>>>(part);
  scan_write<<<NSCAN, 1024, 0, stream>>>(deg, part, rs);
  bucket_scatter<<<NB, 256, 0, stream>>>(ebuf, boff, rs, adj);

  const int GEMMG = (NNODES + 63) / 64;
  // layer 0: x -> ha (relu)
  gemm_mfma<4, 1><<<GEMMG, 256, 0, stream>>>(d_in[0], wts, Wt, 16384, 16512, G, al, ar, flags);
  aggregate4<4, 1, 0><<<NNODES / 4, 256, 0, stream>>>(G, al, ar, wts, 16640, rs, adj, ha, flags);
  // layer 1: ha -> hb (relu)
  gemm_mfma<4, 0><<<GEMMG, 256, 0, stream>>>(ha, wts, Wt + 16384, 33152, 33280, G, al, ar, flags);
  aggregate4<4, 1, 0><<<NNODES / 4, 256, 0, stream>>>(G, al, ar, wts, 33408, rs, adj, hb, flags);
  // layer 2: hb -> out (no relu, H=1, fused output conversion)
  gemm_mfma<1, 0><<<GEMMG, 256, 0, stream>>>(hb, wts, Wt + 32768, 49920, 50048, G, al, ar, flags);
  aggregate4<1, 0, 1><<<NNODES / 4, 256, 0, stream>>>(G, al, ar, wts, 50176, rs, adj, d_out, flags);
}

// Round 10
// 368.461 us; speedup vs baseline: 1.2482x; 1.2482x over previous
//
#include <hip/hip_runtime.h>
#include <hip/hip_bf16.h>
#include <hip/hip_fp16.h>

#define NNODES 100000
#define NEDGES 1600000
#define ETOT   (NEDGES + NNODES)
#define SCANB  1024
#define NSCAN  ((NNODES + SCANB - 1) / SCANB)  // 98
#define NB     782                              // buckets of 128 nodes (dst>>7)
#define NBINBLK 256                             // blocks for privatized binning

typedef _Float16 half8 __attribute__((ext_vector_type(8)));
typedef float f32x4 __attribute__((ext_vector_type(4)));

struct WSrc { const void* p[12]; };

__device__ __forceinline__ float ld_f(const void* p, long i, int f32) {
  if (f32) return ((const float*)p)[i];
  return __bfloat162float(((const __hip_bfloat16*)p)[i]);
}

__device__ __forceinline__ unsigned short f2bf_bits(float v) {
  __hip_bfloat16 b = __float2bfloat16(v);
  return __builtin_bit_cast(unsigned short, b);
}

// ---------------- dtype detection ----------------
// flags[0]: 1 => edge_index is int64, else int32
// flags[1]: 1 => float buffers are fp32, else bf16
__global__ void detect_kernel(const void* xraw, const void* eraw, int* flags) {
  __shared__ int cnt0, cnt1;
  if (threadIdx.x == 0) { cnt0 = 0; cnt1 = 0; }
  __syncthreads();
  const int* e32 = (const int*)eraw;
  int nz = 0;
  for (int i = threadIdx.x; i < 2048; i += blockDim.x) nz += (e32[2 * i + 1] != 0);
  const unsigned short* xs = (const unsigned short*)xraw;
  int weird = 0;
  for (int i = threadIdx.x; i < 4096; i += blockDim.x) {
    unsigned short u = xs[2 * i];
    int ex = (u >> 7) & 0xFF;
    weird += (ex > 168 || (ex < 88 && ex != 0)) ? 1 : 0;
  }
  atomicAdd(&cnt0, nz);
  atomicAdd(&cnt1, weird);
  __syncthreads();
  if (threadIdx.x == 0) {
    flags[0] = (cnt0 < 1024) ? 1 : 0;
    flags[1] = (cnt1 > 512) ? 1 : 0;
  }
}

// ---------------- weights to fp32 (+ fused fp16 W^T production) ----------------
__global__ void conv_wts_kernel(WSrc wsrc, float* dst, __half* Wt, const int* flags) {
  const int start[13] = {0, 16384, 16512, 16640, 16768, 33152, 33280, 33408,
                         33536, 49920, 50048, 50176, 50304};
  int f32 = flags[1];
  int stride = gridDim.x * blockDim.x;
  for (int i = blockIdx.x * blockDim.x + threadIdx.x; i < 50304; i += stride) {
    int s = 0;
    while (start[s + 1] <= i) s++;
    float v = ld_f(wsrc.p[s], i - start[s], f32);
    dst[i] = v;
    if (s == 0 || s == 4 || s == 8) {  // W regions -> transposed fp16 Wt[layer][col][k]
      int layer = s >> 2;
      int rem = i - start[s];
      int k = rem >> 7, c = rem & 127;
      Wt[layer * 16384 + c * 128 + k] = __float2half(v);
    }
  }
}

// ---------------- bucketed CSR build (block-privatized) ----------------
__device__ __forceinline__ void load_edge(const void* raw, int i64, long e, int& s, int& d) {
  if (i64) {
    const long long* r = (const long long*)raw;
    s = (int)r[e];
    d = (int)r[NEDGES + e];
  } else {
    const int* r = (const int*)raw;
    s = r[e];
    d = r[NEDGES + e];
  }
}

__device__ __forceinline__ int load_dst(const void* raw, int i64, long e) {
  if (i64) return (int)((const long long*)raw)[NEDGES + e];
  return ((const int*)raw)[NEDGES + e];
}

// privatized bucket histogram: LDS counts, one global add per (block,bucket)
__global__ __launch_bounds__(256) void binhist(const void* raw, const int* flags, int* bcnt) {
  __shared__ int h[NB];
  for (int t = threadIdx.x; t < NB; t += 256) h[t] = 0;
  __syncthreads();
  int i64 = flags[0];
  long per = (NEDGES + NBINBLK - 1) / NBINBLK;
  long lo = (long)blockIdx.x * per;
  long hi = lo + per; if (hi > NEDGES) hi = NEDGES;
  for (long e = lo + threadIdx.x; e < hi; e += 256)
    atomicAdd(&h[load_dst(raw, i64, e) >> 7], 1);
  __syncthreads();
  for (int t = threadIdx.x; t < NB; t += 256) {
    int c = h[t];
    if (c) atomicAdd(&bcnt[t], c);
  }
}

__global__ __launch_bounds__(1024) void binscan(const int* bcnt, int* boff, int* bcur) {
  __shared__ int lds[1024];
  int t = threadIdx.x;
  int x = (t < NB) ? bcnt[t] : 0;
  lds[t] = x;
  __syncthreads();
  for (int off = 1; off < 1024; off <<= 1) {
    int v = (t >= off) ? lds[t - off] : 0;
    __syncthreads();
    lds[t] += v;
    __syncthreads();
  }
  int excl = lds[t] - x;
  if (t < NB) { boff[t] = excl; bcur[t] = excl; }
  if (t == 0) boff[NB] = NEDGES;
}

// privatized placement. ebuf entry packed: src (17 bits) | (dst&127) << 17
__global__ __launch_bounds__(256) void binplace(const void* raw, const int* flags, int* bcur,
                                                int* ebuf) {
  __shared__ int hist[NB];
  __shared__ int base[NB];
  int i64 = flags[0];
  long per = (NEDGES + NBINBLK - 1) / NBINBLK;
  long lo = (long)blockIdx.x * per;
  long hi = lo + per; if (hi > NEDGES) hi = NEDGES;
  for (int t = threadIdx.x; t < NB; t += 256) hist[t] = 0;
  __syncthreads();
  for (long e = lo + threadIdx.x; e < hi; e += 256)
    atomicAdd(&hist[load_dst(raw, i64, e) >> 7], 1);
  __syncthreads();
  for (int t = threadIdx.x; t < NB; t += 256) {
    int c = hist[t];
    base[t] = c ? atomicAdd(&bcur[t], c) : 0;
    hist[t] = 0;
  }
  __syncthreads();
  for (long e = lo + threadIdx.x; e < hi; e += 256) {
    int s, d;
    load_edge(raw, i64, e, s, d);
    int b = d >> 7;
    int pos = base[b] + atomicAdd(&hist[b], 1);
    ebuf[pos] = s | ((d & 127) << 17);
  }
}

// per-bucket degree histogram (LDS), real edges only
__global__ __launch_bounds__(256) void deghist(const int* ebuf, const int* boff, int* deg) {
  __shared__ int h[128];
  int b = blockIdx.x, t = threadIdx.x;
  if (t < 128) h[t] = 0;
  __syncthreads();
  int beg = boff[b], end = boff[b + 1];
  for (int i = beg + t; i < end; i += 256) atomicAdd(&h[ebuf[i] >> 17], 1);
  __syncthreads();
  int node = b * 128 + t;
  if (t < 128 && node < NNODES) deg[node] = h[t];
}

// ---------------- multi-block exclusive scan of (deg[i]+1) ----------------
__global__ __launch_bounds__(1024) void scan_part(const int* deg, int* part) {
  __shared__ int lds[SCANB];
  int b = blockIdx.x, t = threadIdx.x;
  int idx = b * SCANB + t;
  lds[t] = (idx < NNODES) ? deg[idx] + 1 : 0;
  __syncthreads();
  for (int off = 512; off > 0; off >>= 1) {
    if (t < off) lds[t] += lds[t + off];
    __syncthreads();
  }
  if (t == 0) part[b] = lds[0];
}

__global__ __launch_bounds__(128) void scan_tops(int* part) {
  __shared__ int lds[128];
  int t = threadIdx.x;
  lds[t] = (t < NSCAN) ? part[t] : 0;
  __syncthreads();
  for (int off = 1; off < 128; off <<= 1) {
    int v = (t >= off) ? lds[t - off] : 0;
    __syncthreads();
    lds[t] += v;
    __syncthreads();
  }
  if (t < NSCAN) part[t] = (t == 0) ? 0 : lds[t - 1];
}

__global__ __launch_bounds__(1024) void scan_write(const int* deg, const int* part, int* rs) {
  __shared__ int lds[SCANB];
  int b = blockIdx.x, t = threadIdx.x;
  int idx = b * SCANB + t;
  int x = (idx < NNODES) ? deg[idx] + 1 : 0;
  lds[t] = x;
  __syncthreads();
  for (int off = 1; off < SCANB; off <<= 1) {
    int v = (t >= off) ? lds[t - off] : 0;
    __syncthreads();
    lds[t] += v;
    __syncthreads();
  }
  int incl = part[b] + lds[t];
  int excl = incl - x;
  if (idx < NNODES) rs[idx] = excl;
  if (idx == NNODES - 1) rs[NNODES] = incl;
}

// per-bucket scatter with LDS cursors; adj writes land in a contiguous window
__global__ __launch_bounds__(256) void bucket_scatter(const int* ebuf, const int* boff,
                                                      const int* rs, int* adj) {
  __shared__ int cur[128];
  int b = blockIdx.x, t = threadIdx.x;
  int node = b * 128 + t;
  if (t < 128) cur[t] = (node < NNODES) ? rs[node] : 0;
  __syncthreads();
  int beg = boff[b], end = boff[b + 1];
  for (int i = beg + t; i < end; i += 256) {
    int v = ebuf[i];
    int pos = atomicAdd(&cur[v >> 17], 1);
    adj[pos] = v & 0x1FFFF;
  }
  __syncthreads();
  if (t < 128 && node < NNODES) adj[cur[t]] = node;  // self-loop appended last
}

// ---------------- MFMA GEMM + fused attention terms ----------------
template <int H, int SRC>  // SRC: 1 = raw x (bf16/fp32 by flag), 0 = fp16
__global__ __launch_bounds__(256) void gemm_mfma(const void* Araw, const float* wts,
                                                 const __half* Wt, int as_off, int ad_off,
                                                 __half* G, float* al, float* ar,
                                                 const int* flags) {
  __shared__ unsigned short Wl[128 * 128];
  __shared__ unsigned short Al[64 * 128];
  const int tid = threadIdx.x;
  const int rowbase = blockIdx.x * 64;
  for (int i = tid; i < 2048; i += 256) {
    int col = i >> 4, kc = i & 15;
    ((uint4*)Wl)[col * 16 + (kc ^ (col & 7))] = ((const uint4*)Wt)[i];
  }
  if (SRC == 0) {
    const __half* A = (const __half*)Araw;
    for (int i = tid; i < 1024; i += 256) {
      int row = i >> 4, kc = i & 15;
      int grow = rowbase + row;
      uint4 v = {0, 0, 0, 0};
      if (grow < NNODES) v = *(const uint4*)&A[(size_t)grow * 128 + kc * 8];
      ((uint4*)Al)[row * 16 + (kc ^ (row & 7))] = v;
    }
  } else {
    int f32 = flags[1];
    for (int i = tid; i < 1024; i += 256) {
      int row = i >> 4, kc = i & 15;
      int grow = rowbase + row;
      _Float16 tmp[8];
#pragma unroll
      for (int j = 0; j < 8; j++) tmp[j] = (_Float16)0.f;
      if (grow < NNODES) {
        if (f32) {
          const float* A = (const float*)Araw;
#pragma unroll
          for (int j = 0; j < 8; j++) tmp[j] = (_Float16)A[(size_t)grow * 128 + kc * 8 + j];
        } else {
          const __hip_bfloat16* A = (const __hip_bfloat16*)Araw;
#pragma unroll
          for (int j = 0; j < 8; j++)
            tmp[j] = (_Float16)__bfloat162float(A[(size_t)grow * 128 + kc * 8 + j]);
        }
      }
      ((uint4*)Al)[row * 16 + (kc ^ (row & 7))] = *(const uint4*)tmp;
    }
  }
  __syncthreads();
  int wv = tid >> 6, l = tid & 63;
  int lr = l & 15, lg = l >> 4;
  f32x4 acc[8];
#pragma unroll
  for (int n = 0; n < 8; n++) acc[n] = (f32x4){0.f, 0.f, 0.f, 0.f};
  int arow = wv * 16 + lr;
#pragma unroll
  for (int ks = 0; ks < 4; ks++) {
    half8 a = *(const half8*)&Al[(arow * 16 + ((ks * 4 + lg) ^ (arow & 7))) * 8];
#pragma unroll
    for (int n = 0; n < 8; n++) {
      int wrow = n * 16 + lr;
      half8 bf = *(const half8*)&Wl[(wrow * 16 + ((ks * 4 + lg) ^ (wrow & 7))) * 8];
      acc[n] = __builtin_amdgcn_mfma_f32_16x16x32_f16(a, bf, acc[n], 0, 0, 0);
    }
  }
  float as_row[8], ad_row[8];
#pragma unroll
  for (int n = 0; n < 8; n++) {
    as_row[n] = wts[as_off + n * 16 + lr];
    ad_row[n] = wts[ad_off + n * 16 + lr];
  }
  if (H == 4) {
    float pa[4][4], pb[4][4];
#pragma unroll
    for (int j = 0; j < 4; j++)
#pragma unroll
      for (int h = 0; h < 4; h++) {
        pa[j][h] = acc[2 * h][j] * as_row[2 * h] + acc[2 * h + 1][j] * as_row[2 * h + 1];
        pb[j][h] = acc[2 * h][j] * ad_row[2 * h] + acc[2 * h + 1][j] * ad_row[2 * h + 1];
      }
#pragma unroll
    for (int msk = 1; msk <= 8; msk <<= 1)
#pragma unroll
      for (int j = 0; j < 4; j++)
#pragma unroll
        for (int h = 0; h < 4; h++) {
          pa[j][h] += __shfl_xor(pa[j][h], msk, 64);
          pb[j][h] += __shfl_xor(pb[j][h], msk, 64);
        }
    if (lr == 0) {
#pragma unroll
      for (int j = 0; j < 4; j++) {
        int gr = rowbase + wv * 16 + lg * 4 + j;
        if (gr < NNODES) {
#pragma unroll
          for (int h = 0; h < 4; h++) {
            al[(size_t)gr * 4 + h] = pa[j][h];
            ar[(size_t)gr * 4 + h] = pb[j][h];
          }
        }
      }
    }
  } else {
    float pa[4], pb[4];
#pragma unroll
    for (int j = 0; j < 4; j++) {
      pa[j] = 0.f;
      pb[j] = 0.f;
#pragma unroll
      for (int n = 0; n < 8; n++) {
        pa[j] = fmaf(acc[n][j], as_row[n], pa[j]);
        pb[j] = fmaf(acc[n][j], ad_row[n], pb[j]);
      }
    }
#pragma unroll
    for (int msk = 1; msk <= 8; msk <<= 1)
#pragma unroll
      for (int j = 0; j < 4; j++) {
        pa[j] += __shfl_xor(pa[j], msk, 64);
        pb[j] += __shfl_xor(pb[j], msk, 64);
      }
    if (lr == 0) {
#pragma unroll
      for (int j = 0; j < 4; j++) {
        int gr = rowbase + wv * 16 + lg * 4 + j;
        if (gr < NNODES) { al[gr] = pa[j]; ar[gr] = pb[j]; }
      }
    }
  }
  __syncthreads();
#pragma unroll
  for (int n = 0; n < 8; n++)
#pragma unroll
    for (int j = 0; j < 4; j++) {
      int r = wv * 16 + lg * 4 + j;
      Al[r * 128 + n * 16 + lr] = __builtin_bit_cast(unsigned short, (_Float16)acc[n][j]);
    }
  __syncthreads();
  for (int i = tid; i < 1024; i += 256) {
    int row = i >> 4, kc = i & 15;
    int grow = rowbase + row;
    if (grow < NNODES) *(uint4*)&G[(size_t)grow * 128 + kc * 8] = ((const uint4*)Al)[i];
  }
}

// ---------------- flash aggregation: 16-edge chunks, 4 lanes/edge, prefetched ----------------
// One wave per dst node. Lane l: edge slot (l>>2), head (l&3).
// Per chunk: (1) issue next chunk's adj load (branchless clamp), (2) stage the 16
// G-row pairs (readlane row broadcast -> saddr loads), (3) issue next chunk's al
// load, (4) softmax + fma run under all the in-flight loads.
template <int H, int RELU, int OUTCONV>
__global__ __launch_bounds__(256) void aggregate5(const __half* G, const float* al, const float* ar,
                                                  const float* wts, int b_off, const int* rs,
                                                  const int* adj, void* out, const int* flags) {
  int node = blockIdx.x * 4 + (threadIdx.x >> 6);
  if (node >= NNODES) return;
  int l = threadIdx.x & 63;
  int hh = (l & 3) & (H - 1);
  int hA = l >> 4;
  float ar_d = ar[(size_t)node * H + hh];
  int beg = rs[node], end = rs[node + 1];
  float m = -1e30f, sum = 0.f;
  float accx = 0.f, accy = 0.f;
  // chunk-0 adj+al (clamped, branchless)
  int slot = beg + (l >> 2);
  bool valid = slot < end;
  int sc = slot < ETOT - 1 ? slot : ETOT - 1;
  int s = adj[sc];
  float av = al[(size_t)s * H + hh];
  for (int base = beg; base < end; base += 16) {
    int nj = end - base; if (nj > 16) nj = 16;  // wave-uniform
    // (1) issue next chunk's adj load early
    int slot2 = base + 16 + (l >> 2);
    bool valid2 = slot2 < end;
    int sc2 = slot2 < ETOT - 1 ? slot2 : ETOT - 1;
    int s2 = adj[sc2];
    // (2) stage current chunk's 16 G-row channel pairs (independent of s2)
    __half2 g[16];
#pragma unroll
    for (int j = 0; j < 16; j++) {
      if (j < nj) {
        int sj = __builtin_amdgcn_readlane(s, 4 * j);
        g[j] = *(const __half2*)&G[(size_t)sj * 128 + 2 * l];
      }
    }
    // (3) next chunk's al (waits only on s2; overlaps softmax+fma below)
    float av2 = al[(size_t)s2 * H + hh];
    // (4) softmax on current chunk
    float v = av + ar_d;
    float e = valid ? ((v > 0.f) ? v : 0.2f * v) : -1e30f;
    float cm = e;
    cm = fmaxf(cm, __shfl_xor(cm, 4, 64));
    cm = fmaxf(cm, __shfl_xor(cm, 8, 64));
    cm = fmaxf(cm, __shfl_xor(cm, 16, 64));
    cm = fmaxf(cm, __shfl_xor(cm, 32, 64));
    float mn = fmaxf(m, cm);
    float scale = __expf(m - mn);
    float p = __expf(e - mn);
    float cs = p;
    cs += __shfl_xor(cs, 4, 64);
    cs += __shfl_xor(cs, 8, 64);
    cs += __shfl_xor(cs, 16, 64);
    cs += __shfl_xor(cs, 32, 64);
    sum = sum * scale + cs;
    m = mn;
    float scA = __shfl(scale, hA, 64);
    accx *= scA;
    accy *= scA;
#pragma unroll
    for (int j = 0; j < 16; j++) {
      if (j < nj) {
        float aA = __shfl(p, 4 * j + hA, 64);
        float2 g2 = __half22float2(g[j]);
        accx = fmaf(aA, g2.x, accx);
        accy = fmaf(aA, g2.y, accy);
      }
    }
    // rotate prefetched state
    s = s2;
    av = av2;
    valid = valid2;
  }
  float inv = 1.f / (__shfl(sum, hA, 64) + 1e-16f);
  float2 b2 = *(const float2*)&wts[b_off + 2 * l];
  float ox = accx * inv + b2.x;
  float oy = accy * inv + b2.y;
  if (RELU) {
    ox = fmaxf(ox, 0.f);
    oy = fmaxf(oy, 0.f);
  }
  size_t oi = (size_t)node * 128 + 2 * l;
  if (OUTCONV) {
    if (flags[1]) {
      *(float2*)&((float*)out)[oi] = make_float2(ox, oy);
    } else {
      *(ushort2*)&((unsigned short*)out)[oi] = make_ushort2(f2bf_bits(ox), f2bf_bits(oy));
    }
  } else {
    *(__half2*)&((__half*)out)[oi] = __floats2half2_rn(ox, oy);
  }
}

extern "C" void kernel_launch(void* const* d_in, const int* in_sizes, int n_in,
                              void* d_out, int out_size, void* d_ws, size_t ws_size,
                              hipStream_t stream) {
  char* ws = (char*)d_ws;
  size_t cur = 0;
  auto alloc = [&](size_t bytes) {
    size_t o = cur;
    cur += (bytes + 255) & ~(size_t)255;
    return o;
  };
  size_t off_flags = alloc(256);
  size_t off_wts = alloc(50304 * 4);
  size_t off_wt = alloc(3 * 16384 * 2);
  size_t off_ebuf = alloc((size_t)NEDGES * 4);
  size_t off_bcnt = alloc((size_t)NB * 4);
  size_t off_boff = alloc(((size_t)NB + 1) * 4);
  size_t off_bcur = alloc((size_t)NB * 4);
  size_t off_deg = alloc((size_t)NNODES * 4);
  size_t off_part = alloc((size_t)NSCAN * 4 + 256);
  size_t off_rs = alloc(((size_t)NNODES + 1) * 4);
  size_t off_adj = alloc((size_t)ETOT * 4);
  size_t off_al = alloc((size_t)NNODES * 4 * 4);
  size_t off_ar = alloc((size_t)NNODES * 4 * 4);
  size_t off_g = alloc((size_t)NNODES * 128 * 2);
  size_t off_ha = alloc((size_t)NNODES * 128 * 2);
  size_t off_hb = alloc((size_t)NNODES * 128 * 2);

  int* flags = (int*)(ws + off_flags);
  float* wts = (float*)(ws + off_wts);
  __half* Wt = (__half*)(ws + off_wt);
  int* ebuf = (int*)(ws + off_ebuf);
  int* bcnt = (int*)(ws + off_bcnt);
  int* boff = (int*)(ws + off_boff);
  int* bcur = (int*)(ws + off_bcur);
  int* deg = (int*)(ws + off_deg);
  int* part = (int*)(ws + off_part);
  int* rs = (int*)(ws + off_rs);
  int* adj = (int*)(ws + off_adj);
  float* al = (float*)(ws + off_al);
  float* ar = (float*)(ws + off_ar);
  __half* G = (__half*)(ws + off_g);
  __half* ha = (__half*)(ws + off_ha);
  __half* hb = (__half*)(ws + off_hb);

  detect_kernel<<<1, 256, 0, stream>>>(d_in[0], d_in[1], flags);

  WSrc wsrc;
  for (int i = 0; i < 12; i++) wsrc.p[i] = d_in[2 + i];
  conv_wts_kernel<<<64, 256, 0, stream>>>(wsrc, wts, Wt, flags);

  (void)hipMemsetAsync(bcnt, 0, (size_t)NB * 4, stream);
  binhist<<<NBINBLK, 256, 0, stream>>>(d_in[1], flags, bcnt);
  binscan<<<1, 1024, 0, stream>>>(bcnt, boff, bcur);
  binplace<<<NBINBLK, 256, 0, stream>>>(d_in[1], flags, bcur, ebuf);
  deghist<<<NB, 256, 0, stream>>>(ebuf, boff, deg);
  scan_part<<<NSCAN, 1024, 0, stream>>>(deg, part);
  scan_tops<<<1, 128, 0, stream>>>(part);
  scan_write<<<NSCAN, 1024, 0, stream>>>(deg, part, rs);
  bucket_scatter<<<NB, 256, 0, stream>>>(ebuf, boff, rs, adj);

  const int GEMMG = (NNODES + 63) / 64;
  // layer 0: x -> ha (relu)
  gemm_mfma<4, 1><<<GEMMG, 256, 0, stream>>>(d_in[0], wts, Wt, 16384, 16512, G, al, ar, flags);
  aggregate5<4, 1, 0><<<NNODES / 4, 256, 0, stream>>>(G, al, ar, wts, 16640, rs, adj, ha, flags);
  // layer 1: ha -> hb (relu)
  gemm_mfma<4, 0><<<GEMMG, 256, 0, stream>>>(ha, wts, Wt + 16384, 33152, 33280, G, al, ar, flags);
  aggregate5<4, 1, 0><<<NNODES / 4, 256, 0, stream>>>(G, al, ar, wts, 33408, rs, adj, hb, flags);
  // layer 2: hb -> out (no relu, H=1, fused output conversion)
  gemm_mfma<1, 0><<<GEMMG, 256, 0, stream>>>(hb, wts, Wt + 32768, 49920, 50048, G, al, ar, flags);
  aggregate5<1, 0, 1><<<NNODES / 4, 256, 0, stream>>>(G, al, ar, wts, 50176, rs, adj, d_out, flags);
}